// Round 8
// baseline (887.117 us; speedup 1.0000x reference)
//
#include <hip/hip_runtime.h>
#include <hip/hip_bf16.h>
#include <stdint.h>

// MoE FFN: sigmoid router (group-limited greedy top-8 of 64), SwiGLU experts
// (1024->512->1024) + shared expert (1024->2048->1024). All inputs fp32.
// R11: B path rebuilt. R8-R10's B staging (16 scalar dword loads + b128
// writes w/ 16-way bank conflict) replaced by: float4 loads along N (4 wide
// loads/thread/step), cvt_pk, b64 writes into subtiled [k/4][n/16][4][16]
// bf16 LDS, fragments via ds_read_b64_tr_b16 (HW transpose, conflict-free:
// each 16-lane group reads one contiguous 128B chunk). fp32-native weights
// kept (no transpose prepass). A: 3-slot gl2lds ring 2-ahead (R10's no-op
// source swizzle reverted). B regs 2-deep ping-pong; writeB's implicit
// vmcnt wait is the only VMEM gate (A(t+1) older -> drains with it).
// Worklist balancing (R6) + combine-not-atomics (R5) kept.

#define S_TOK 4096
#define C_DIM 1024
#define E_NUM 64
#define H_DIM 512
#define HS_DIM 2048
#define ROWS_TOTAL (S_TOK * 8)
#define T_TILES 320

typedef __attribute__((ext_vector_type(8))) short short8;
typedef __attribute__((ext_vector_type(4))) float f32x4;
typedef __attribute__((ext_vector_type(2))) unsigned int uint2v;

static __device__ __forceinline__ unsigned short f2bf(float f) {
    union { float f; uint32_t u; } v; v.f = f;
    uint32_t u = v.u;
    u += 0x7fffu + ((u >> 16) & 1u);   // RNE
    return (unsigned short)(u >> 16);
}

static __device__ __forceinline__ void gl2lds16(const void* g, void* l) {
    __builtin_amdgcn_global_load_lds(
        (const __attribute__((address_space(1))) uint32_t*)g,
        (__attribute__((address_space(3))) uint32_t*)l, 16, 0, 0);
}

static __device__ __forceinline__ uint32_t cvtpk(float a, float b) {
    uint32_t r;
    asm("v_cvt_pk_bf16_f32 %0, %1, %2" : "=v"(r) : "v"(a), "v"(b));
    return r;
}

static __device__ __forceinline__ uint2v tr64(unsigned addr) {
    uint2v r;
    asm volatile("ds_read_b64_tr_b16 %0, %1" : "=v"(r) : "v"(addr));
    return r;
}

// ---------------- router part 1: scores = sigmoid(x @ rw^T), fp32 ----------------
__global__ __launch_bounds__(256)
void router_scores_k(const float* __restrict__ x, const float* __restrict__ rw,
                     float* __restrict__ scores, int* __restrict__ counts) {
    if (blockIdx.x == 0 && threadIdx.x < E_NUM) counts[threadIdx.x] = 0;
    int t0 = blockIdx.x * 32;
    __shared__ float xs[32][36];
    __shared__ float wsm[64][36];
    int t = threadIdx.x;
    int tx = t & 15, ty = t >> 4;
    float acc[2][4] = {};
    for (int k0 = 0; k0 < C_DIM; k0 += 32) {
        {
            int r = t >> 3, c = t & 7;
            *(float4*)&xs[r][c * 4] = *(const float4*)(x + (size_t)(t0 + r) * C_DIM + k0 + c * 4);
        }
        #pragma unroll
        for (int i = 0; i < 2; i++) {
            int idx = t + 256 * i;
            int r = idx >> 3, c = idx & 7;
            *(float4*)&wsm[r][c * 4] = *(const float4*)(rw + (size_t)r * C_DIM + k0 + c * 4);
        }
        __syncthreads();
        #pragma unroll
        for (int kk = 0; kk < 32; kk += 4) {
            float4 a0 = *(const float4*)&xs[ty * 2 + 0][kk];
            float4 a1 = *(const float4*)&xs[ty * 2 + 1][kk];
            #pragma unroll
            for (int j = 0; j < 4; j++) {
                float4 b = *(const float4*)&wsm[tx * 4 + j][kk];
                acc[0][j] += a0.x * b.x + a0.y * b.y + a0.z * b.z + a0.w * b.w;
                acc[1][j] += a1.x * b.x + a1.y * b.y + a1.z * b.z + a1.w * b.w;
            }
        }
        __syncthreads();
    }
    #pragma unroll
    for (int i = 0; i < 2; i++)
        #pragma unroll
        for (int j = 0; j < 4; j++)
            scores[(size_t)(t0 + ty * 2 + i) * E_NUM + tx * 4 + j] =
                1.f / (1.f + __expf(-acc[i][j]));
}

// ---------------- router part 2: wave-parallel grouped top-k ----------------
__global__ __launch_bounds__(256)
void topk_k(const float* __restrict__ scores, const float* __restrict__ ebias,
            int* __restrict__ topk_idx, float* __restrict__ topk_w,
            int* __restrict__ counts) {
    int t = blockIdx.x * 4 + (threadIdx.x >> 6);
    int e = threadIdx.x & 63;
    float sc = scores[(size_t)t * E_NUM + e];
    float sb = sc + ebias[e];
    float m1 = sb, m2 = -1e30f;
    #pragma unroll
    for (int off = 1; off <= 4; off <<= 1) {
        float o1 = __shfl_xor(m1, off);
        float o2 = __shfl_xor(m2, off);
        float hi = fmaxf(m1, o1), lo = fminf(m1, o1);
        m2 = fmaxf(lo, fmaxf(m2, o2));
        m1 = hi;
    }
    float grp = m1 + m2;
    float grpv[8];
    #pragma unroll
    for (int g = 0; g < 8; g++) grpv[g] = __shfl(grp, g * 8);
    unsigned gsel = 0;
    #pragma unroll
    for (int k = 0; k < 4; k++) {
        float best = -1e30f; int bi = 0;
        #pragma unroll
        for (int g = 0; g < 8; g++)
            if (!((gsel >> g) & 1) && grpv[g] > best) { best = grpv[g]; bi = g; }
        gsel |= 1u << bi;
    }
    float val = ((gsel >> (e >> 3)) & 1) ? sb : -1e30f;
    int idx[8]; float sv[8]; float wsum = 0.f;
    #pragma unroll
    for (int k = 0; k < 8; k++) {
        uint32_t u = __float_as_uint(val);
        uint32_t mu = (u & 0x80000000u) ? ~u : (u | 0x80000000u);
        unsigned long long key = ((unsigned long long)mu << 6) | (unsigned long long)(63 - e);
        #pragma unroll
        for (int off = 32; off; off >>= 1) {
            unsigned long long ok = __shfl_xor(key, off);
            if (ok > key) key = ok;
        }
        int win = 63 - (int)(key & 63ull);
        idx[k] = win;
        sv[k] = __shfl(sc, win);
        wsum += sv[k];
        if (e == win) val = -1e30f;
    }
    float inv = 1.f / (wsum + 1e-20f);
    if (e < 8) {
        topk_idx[t * 8 + e] = idx[e];
        topk_w[t * 8 + e] = sv[e] * inv;
        atomicAdd(&counts[idx[e]], 1);
    }
}

// exclusive scan over 64 expert counts + m-tile worklist build, one wave
__global__ void scan_k(const int* __restrict__ counts, int* __restrict__ base,
                       int* __restrict__ cursor, int* __restrict__ tile_e,
                       int* __restrict__ tile_m0) {
    int e = threadIdx.x;
    int c = counts[e];
    int s = c;
    #pragma unroll
    for (int off = 1; off < 64; off <<= 1) {
        int o = __shfl_up(s, off);
        if (e >= off) s += o;
    }
    int ex = s - c;
    base[e] = ex;
    cursor[e] = ex;
    int nt = (c + 127) >> 7;
    int ts = nt;
    #pragma unroll
    for (int off = 1; off < 64; off <<= 1) {
        int o = __shfl_up(ts, off);
        if (e >= off) ts += o;
    }
    int tb = ts - nt;
    for (int i = 0; i < nt; i++) { tile_e[tb + i] = e; tile_m0[tb + i] = i * 128; }
    int total = __shfl(ts, 63);
    for (int j = total + e; j < T_TILES; j += 64) tile_e[j] = -1;
}

__global__ void scatter_k(const int* __restrict__ topk_idx, const float* __restrict__ topk_w,
                          int* __restrict__ cursor, int* __restrict__ row_token,
                          float* __restrict__ row_wgt, int* __restrict__ pos_of) {
    int i = blockIdx.x * blockDim.x + threadIdx.x;
    int e = topk_idx[i];
    int pos = atomicAdd(&cursor[e], 1);
    row_token[pos] = i >> 3;
    row_wgt[pos] = topk_w[i];
    pos_of[i] = pos;
}

// ---------------- combine: out[t] += sum_k O[pos_of[t*8+k]] (weights pre-applied) ---
__global__ __launch_bounds__(256)
void combine_k(const float* __restrict__ O, const int* __restrict__ pos_of,
               float* __restrict__ out) {
    int t = blockIdx.x;
    int c = threadIdx.x;
    float4 s = ((const float4*)(out + (size_t)t * C_DIM))[c];
    int p[8];
    #pragma unroll
    for (int k = 0; k < 8; k++) p[k] = pos_of[t * 8 + k];
    #pragma unroll
    for (int k = 0; k < 8; k++) {
        float4 v = ((const float4*)(O + (size_t)p[k] * C_DIM))[c];
        s.x += v.x; s.y += v.y; s.z += v.z; s.w += v.w;
    }
    ((float4*)(out + (size_t)t * C_DIM))[c] = s;
}

// ---------------- prepass: fp32 -> bf16 elementwise (x) ----------------
__global__ void cvt_bf16_k(const float* __restrict__ in, unsigned short* __restrict__ out, int n8) {
    int i = blockIdx.x * blockDim.x + threadIdx.x;
    if (i >= n8) return;
    float4 v0 = ((const float4*)in)[2 * i];
    float4 v1 = ((const float4*)in)[2 * i + 1];
    unsigned short t[8] = { f2bf(v0.x), f2bf(v0.y), f2bf(v0.z), f2bf(v0.w),
                            f2bf(v1.x), f2bf(v1.y), f2bf(v1.z), f2bf(v1.w) };
    ((uint4*)out)[i] = *(uint4*)t;
}

// ---------------- GEMM: C[M,N] = A[M,K](bf16) @ B[K,N](fp32 native), fp32 acc ----
// A: [M][K] bf16 LDS via gl2lds, 3-slot ring staged 2 ahead. B: float4 loads
// along N (2-deep reg ping-pong), cvt_pk, b64 writes into subtiled
// [k/4][n/16][4][16] bf16 LDS (2-buffer); fragments via ds_read_b64_tr_b16.
// FUSED: BN=64 (B1,B2), else BN=128. EPI: 0 SwiGLU->bf16; 1 f32; 2 f32*w
template<bool FUSED, bool GATHER, bool WL, int EPI>
__global__ __launch_bounds__(256, 3)
void gemm2_k(const short* __restrict__ A, const float* __restrict__ B1f,
             const float* __restrict__ B2f, void* __restrict__ Cout,
             int M, int N, int K,
             const int* __restrict__ counts, const int* __restrict__ base,
             const int* __restrict__ row_token, const float* __restrict__ row_wgt,
             const int* __restrict__ tile_e, const int* __restrict__ tile_m0) {
    constexpr int BN = FUSED ? 64 : 128;
    constexpr int NJ = FUSED ? 2 : 4;
    constexpr int CH = BN / 16;            // n-chunks per k-chunk row
    constexpr int BS = BN * 32;            // B LDS shorts per buffer (per matrix)

    int e = 0, m0, Mrows, rowbase = 0;
    if (WL) {
        e = tile_e[blockIdx.y];
        if (e < 0) return;
        m0 = tile_m0[blockIdx.y];
        Mrows = counts[e];
        rowbase = base[e];
    } else {
        m0 = blockIdx.y * 128;
        Mrows = M;
    }
    int n0 = blockIdx.x * BN;
    const float* B1 = B1f + (WL ? (size_t)e * N * K : 0);
    const float* B2 = FUSED ? (B2f + (WL ? (size_t)e * N * K : 0)) : nullptr;

    __shared__ short As[3 * 4096];                 // 3 x 128x32 (24 KB)
    __shared__ short Bs1[2 * BS];
    __shared__ short Bs2[FUSED ? 2 * BS : 16];

    int tid = threadIdx.x;
    int lane = tid & 63, w = tid >> 6;
    int wr = w >> 1, wc = w & 1;
    int quad = lane >> 4, l16 = lane & 15;
    int sr = lane >> 2, sc = lane & 3;

    // A staging pointers (gl2lds; wave w covers rows w*32..w*32+31)
    const short* aptr[2];
    #pragma unroll
    for (int i = 0; i < 2; i++) {
        int row = w * 32 + i * 16 + sr;
        int mrow = m0 + row;
        int cl = mrow < Mrows ? mrow : (Mrows - 1);
        size_t arow;
        if (GATHER)  arow = (size_t)row_token[rowbase + cl];
        else if (WL) arow = (size_t)(rowbase + cl);
        else         arow = (size_t)mrow;
        aptr[i] = A + arow * K + sc * 8;
    }

    // B staging thread map: k-row bk = tid>>3; n-offset bn
    int bk = tid >> 3;
    int bn = FUSED ? (tid & 7) * 8 : (tid & 7) * 16;
    const float* b1g = B1 + (size_t)bk * N + n0 + bn;
    const float* b2g = FUSED ? (B2 + (size_t)bk * N + n0 + bn) : nullptr;
    // subtiled LDS write base (shorts): chunk (bk>>2, bn>>4), row bk&3
    const int wbase = ((bk >> 2) * CH + (bn >> 4)) * 64 + (bk & 3) * 16 + (bn & 15);

    f32x4 acc1[4][NJ] = {};
    f32x4 acc2[FUSED ? 4 : 1][NJ] = {};

    const int nk = K >> 5;

    auto stageA = [&](int slot) {
        #pragma unroll
        for (int i = 0; i < 2; i++) {
            gl2lds16(aptr[i], &As[slot * 4096 + (w * 32 + i * 16) * 32]);
            aptr[i] += 32;
        }
    };
    auto loadB = [&](float (&fb)[16]) {
        if constexpr (FUSED) {
            *(float4*)&fb[0]  = *(const float4*)(b1g);
            *(float4*)&fb[4]  = *(const float4*)(b1g + 4);
            *(float4*)&fb[8]  = *(const float4*)(b2g);
            *(float4*)&fb[12] = *(const float4*)(b2g + 4);
            b2g += (size_t)32 * N;
        } else {
            *(float4*)&fb[0]  = *(const float4*)(b1g);
            *(float4*)&fb[4]  = *(const float4*)(b1g + 4);
            *(float4*)&fb[8]  = *(const float4*)(b1g + 8);
            *(float4*)&fb[12] = *(const float4*)(b1g + 12);
        }
        b1g += (size_t)32 * N;
    };
    auto writeB = [&](int buf, float (&fb)[16]) {
        uint32_t pk[8];
        #pragma unroll
        for (int q = 0; q < 8; q++) pk[q] = cvtpk(fb[2 * q], fb[2 * q + 1]);
        if constexpr (FUSED) {
            *(uint2v*)&Bs1[buf * BS + wbase]     = *(uint2v*)&pk[0];  // cols bn..bn+3
            *(uint2v*)&Bs1[buf * BS + wbase + 4] = *(uint2v*)&pk[2];  // cols bn+4..bn+7
            *(uint2v*)&Bs2[buf * BS + wbase]     = *(uint2v*)&pk[4];
            *(uint2v*)&Bs2[buf * BS + wbase + 4] = *(uint2v*)&pk[6];
        } else {
            *(uint2v*)&Bs1[buf * BS + wbase]      = *(uint2v*)&pk[0];
            *(uint2v*)&Bs1[buf * BS + wbase + 4]  = *(uint2v*)&pk[2];
            *(uint2v*)&Bs1[buf * BS + wbase + 8]  = *(uint2v*)&pk[4];
            *(uint2v*)&Bs1[buf * BS + wbase + 12] = *(uint2v*)&pk[6];
        }
    };
    // tr-read fragment: lane l16 -> col, quad -> k-chunk pair (quad*2, quad*2+1)
    unsigned trb1 = (unsigned)(size_t)&Bs1[0] + (unsigned)(quad * 2 * CH * 128 + l16 * 8);
    unsigned trb2 = FUSED ? ((unsigned)(size_t)&Bs2[0] + (unsigned)(quad * 2 * CH * 128 + l16 * 8)) : 0u;
    auto rdB = [&](unsigned trb, int buf, int nb) -> short8 {
        unsigned a0 = trb + (unsigned)(buf * BS * 2 + nb * 128);
        uint2v lo = tr64(a0);
        uint2v hi = tr64(a0 + CH * 128);
        union { uint32_t u[4]; short8 s; } u;
        u.u[0] = lo[0]; u.u[1] = lo[1]; u.u[2] = hi[0]; u.u[3] = hi[1];
        return u.s;
    };

    float fbA[16], fbB[16];
    // prologue
    stageA(0);
    if (nk > 1) stageA(1);
    {
        float fb0[16];
        loadB(fb0);
        writeB(0, fb0);               // implicit vmcnt wait drains fb0 (+A0,A1)
    }
    if (nk > 1) loadB(fbA);           // tile 1
    asm volatile("s_waitcnt lgkmcnt(0)" ::: "memory");
    __builtin_amdgcn_s_barrier();
    __builtin_amdgcn_sched_barrier(0);

    auto kstep = [&](int t, float (&fbIn)[16], float (&fbOut)[16]) {
        int slot = t % 3;
        int bbuf = t & 1;
        if (t + 2 < nk) { stageA((t + 2) % 3); loadB(fbOut); }

        short8 a[4], b1[NJ], b2[NJ];
        #pragma unroll
        for (int i = 0; i < 4; i++)
            a[i] = *(const short8*)&As[slot * 4096 + (wr * 64 + i * 16 + l16) * 32 + quad * 8];
        #pragma unroll
        for (int j = 0; j < NJ; j++) {
            int nb = wc * (BN / 32) + j;
            b1[j] = rdB(trb1, bbuf, nb);
            if constexpr (FUSED) b2[j] = rdB(trb2, bbuf, nb);
        }
        asm volatile("s_waitcnt lgkmcnt(0)" ::: "memory");
        __builtin_amdgcn_sched_barrier(0);
        #pragma unroll
        for (int i = 0; i < 4; i++)
            #pragma unroll
            for (int j = 0; j < NJ; j++) {
                acc1[i][j] = __builtin_amdgcn_mfma_f32_16x16x32_bf16(a[i], b1[j], acc1[i][j], 0, 0, 0);
                if (FUSED)
                    acc2[i][j] = __builtin_amdgcn_mfma_f32_16x16x32_bf16(a[i], b2[j], acc2[i][j], 0, 0, 0);
            }
        if (t + 1 < nk) {
            writeB((t + 1) & 1, fbIn);    // implicit vmcnt wait on fbIn (drains A(t+1) too)
            asm volatile("s_waitcnt lgkmcnt(0)" ::: "memory");
            __builtin_amdgcn_s_barrier();
            __builtin_amdgcn_sched_barrier(0);
        }
    };

    for (int t = 0; t < nk; t += 2) {
        kstep(t, fbA, fbB);
        if (t + 1 < nk) kstep(t + 1, fbB, fbA);
    }

    constexpr int CB = BN / 2;
    #pragma unroll
    for (int i = 0; i < 4; i++) {
        #pragma unroll
        for (int rr = 0; rr < 4; rr++) {
            int row = m0 + wr * 64 + i * 16 + quad * 4 + rr;
            if (row >= Mrows) continue;
            size_t orow = WL ? (size_t)(rowbase + row) : (size_t)row;
            float scl = 0.f;
            if (EPI == 2) scl = row_wgt[rowbase + row];
            #pragma unroll
            for (int j = 0; j < NJ; j++) {
                int n = n0 + wc * CB + j * 16 + l16;
                float v = acc1[i][j][rr];
                if (EPI == 0) {
                    float u = acc2[i][j][rr];
                    float h = v / (1.f + __expf(-v)) * u;
                    ((unsigned short*)Cout)[orow * N + n] = f2bf(h);
                } else if (EPI == 1) {
                    ((float*)Cout)[orow * N + n] = v;
                } else {
                    ((float*)Cout)[orow * N + n] = v * scl;
                }
            }
        }
    }
}

// ---------------- launch ----------------
extern "C" void kernel_launch(void* const* d_in, const int* in_sizes, int n_in,
                              void* d_out, int out_size, void* d_ws, size_t ws_size,
                              hipStream_t stream) {
    const float* x        = (const float*)d_in[0];
    const float* router_w = (const float*)d_in[1];
    const float* e_bias   = (const float*)d_in[2];
    const float* gate_w   = (const float*)d_in[3];
    const float* up_w     = (const float*)d_in[4];
    const float* down_w   = (const float*)d_in[5];
    const float* sh_gate  = (const float*)d_in[6];
    const float* sh_up    = (const float*)d_in[7];
    const float* sh_down  = (const float*)d_in[8];
    float* out = (float*)d_out;
    char* ws = (char*)d_ws;

    int*   counts    = (int*)(ws);
    int*   base      = (int*)(ws + 256);
    int*   cursor    = (int*)(ws + 512);
    int*   topk_idx  = (int*)(ws + 1024);
    float* topk_w    = (float*)(ws + 1024 + 131072);
    int*   row_token = (int*)(ws + 1024 + 2 * 131072);
    float* row_wgt   = (float*)(ws + 1024 + 3 * 131072);
    float* scoresbuf = (float*)(ws + 1024 + 4 * 131072);           // 1 MB
    int*   pos_of    = (int*)(ws + 1664 * 1024);                   // 128 KB
    int*   tile_e    = (int*)(ws + 1800 * 1024);
    int*   tile_m0   = (int*)(ws + 1808 * 1024);
    const size_t MB = 1u << 20;
    unsigned short* xb = (unsigned short*)(ws + 2 * MB);           // 8 MB
    unsigned short* Hs = (unsigned short*)(ws + 10 * MB);          // 16 MB
    unsigned short* Hr = (unsigned short*)(ws + 26 * MB);          // 32 MB
    float*          O  = (float*)(ws + 70 * MB);                   // 128 MB

    // ---- routing ----
    router_scores_k<<<S_TOK / 32, 256, 0, stream>>>(x, router_w, scoresbuf, counts);
    topk_k<<<S_TOK / 4, 256, 0, stream>>>(scoresbuf, e_bias, topk_idx, topk_w, counts);
    scan_k<<<1, 64, 0, stream>>>(counts, base, cursor, tile_e, tile_m0);
    scatter_k<<<ROWS_TOTAL / 256, 256, 0, stream>>>(topk_idx, topk_w, cursor, row_token, row_wgt, pos_of);

    // ---- prepass: bf16 conversion of x only (weights consumed fp32-native) ----
    cvt_bf16_k<<<S_TOK * C_DIM / 8 / 256, 256, 0, stream>>>(x, xb, S_TOK * C_DIM / 8);

    // ---- shared expert ----
    gemm2_k<true, false, false, 0><<<dim3(HS_DIM / 64, S_TOK / 128, 1), 256, 0, stream>>>(
        (const short*)xb, sh_gate, sh_up, Hs,
        S_TOK, HS_DIM, C_DIM, nullptr, nullptr, nullptr, nullptr, nullptr, nullptr);
    gemm2_k<false, false, false, 1><<<dim3(C_DIM / 128, S_TOK / 128, 1), 256, 0, stream>>>(
        (const short*)Hs, sh_down, nullptr, out,
        S_TOK, C_DIM, HS_DIM, nullptr, nullptr, nullptr, nullptr, nullptr, nullptr);

    // ---- routed experts (worklist-balanced) ----
    gemm2_k<true, true, true, 0><<<dim3(H_DIM / 64, T_TILES, 1), 256, 0, stream>>>(
        (const short*)xb, gate_w, up_w, Hr,
        0, H_DIM, C_DIM, counts, base, row_token, row_wgt, tile_e, tile_m0);
    gemm2_k<false, false, true, 2><<<dim3(C_DIM / 128, T_TILES, 1), 256, 0, stream>>>(
        (const short*)Hr, down_w, nullptr, O,
        0, C_DIM, H_DIM, counts, base, row_token, row_wgt, tile_e, tile_m0);

    // ---- combine routed into out (out already holds shared-expert result) ----
    combine_k<<<S_TOK, 256, 0, stream>>>(O, pos_of, out);
}